// Round 1
// baseline (2331.949 us; speedup 1.0000x reference)
//
#include <hip/hip_runtime.h>

// RegressorHybrid: per-edge 2x 4-layer MLP (128->64->64->32->1, lrelu 0.01)
// Round 1: fp32 correctness baseline.
//   - thread = edge; weights read via wave-uniform (scalar) loads -> v_fmac v,s,v
//   - layer1 accumulates straight from gathered float4 loads (no 128-wide comb)
//   - h1/h2 staged in a private LDS row (stride 66 words -> conflict-free b64)
// Input order: x_src, x_dst, edge_label_index, then ew1,eb1,ww1,wb1,... (4 layers)
// Output: out[0..E) = link_exists, out[E..2E) = link_weight (fp32)

typedef float f4 __attribute__((ext_vector_type(4)));
typedef float f2 __attribute__((ext_vector_type(2)));

#define H 64

__device__ __forceinline__ float lrelu(float x) { return fmaxf(x, 0.01f * x); }

__device__ __forceinline__ float mlp_eval(
    const float* __restrict__ rs, const float* __restrict__ rd,
    float* __restrict__ hrow,
    const float* __restrict__ w1, const float* __restrict__ b1,
    const float* __restrict__ w2, const float* __restrict__ b2,
    const float* __restrict__ w3, const float* __restrict__ b3,
    const float* __restrict__ w4, const float* __restrict__ b4)
{
    float acc[H];
#pragma unroll
    for (int j = 0; j < H; ++j) acc[j] = b1[j];

    // ---- layer 1, src half (k = 0..63), prefetched float4 gather loads ----
    f4 nxt = *(const f4*)(rs);
#pragma unroll 1
    for (int c = 0; c < 16; ++c) {
        f4 xv = nxt;
        nxt = (c < 15) ? *(const f4*)(rs + 4 * (c + 1)) : *(const f4*)(rd);
#pragma unroll
        for (int kk = 0; kk < 4; ++kk) {
            const float* wr = w1 + (4 * c + kk) * H;   // wave-uniform -> s_load
            float x = xv[kk];
#pragma unroll
            for (int j = 0; j < H; ++j) acc[j] = fmaf(x, wr[j], acc[j]);
        }
    }
    // ---- layer 1, dst half (k = 64..127) ----
#pragma unroll 1
    for (int c = 0; c < 16; ++c) {
        f4 xv = nxt;
        if (c < 15) nxt = *(const f4*)(rd + 4 * (c + 1));
#pragma unroll
        for (int kk = 0; kk < 4; ++kk) {
            const float* wr = w1 + (64 + 4 * c + kk) * H;
            float x = xv[kk];
#pragma unroll
            for (int j = 0; j < H; ++j) acc[j] = fmaf(x, wr[j], acc[j]);
        }
    }
#pragma unroll
    for (int j = 0; j < H; j += 2) {
        f2 v; v.x = lrelu(acc[j]); v.y = lrelu(acc[j + 1]);
        *(f2*)(hrow + j) = v;                          // h1 -> private LDS row
    }

    // ---- layer 2: 64 -> 64 ----
#pragma unroll
    for (int j = 0; j < H; ++j) acc[j] = b2[j];
#pragma unroll 1
    for (int c = 0; c < 32; ++c) {
        f2 hv = *(const f2*)(hrow + 2 * c);            // ds_read_b64, 2-way = free
#pragma unroll
        for (int kk = 0; kk < 2; ++kk) {
            const float* wr = w2 + (2 * c + kk) * H;
            float x = hv[kk];
#pragma unroll
            for (int j = 0; j < H; ++j) acc[j] = fmaf(x, wr[j], acc[j]);
        }
    }
#pragma unroll
    for (int j = 0; j < H; j += 2) {
        f2 v; v.x = lrelu(acc[j]); v.y = lrelu(acc[j + 1]);
        *(f2*)(hrow + j) = v;                          // h2 overwrites h1
    }

    // ---- layer 3: 64 -> 32 (result stays in regs) ----
    float a3[32];
#pragma unroll
    for (int j = 0; j < 32; ++j) a3[j] = b3[j];
#pragma unroll 1
    for (int c = 0; c < 32; ++c) {
        f2 hv = *(const f2*)(hrow + 2 * c);
#pragma unroll
        for (int kk = 0; kk < 2; ++kk) {
            const float* wr = w3 + (2 * c + kk) * 32;
            float x = hv[kk];
#pragma unroll
            for (int j = 0; j < 32; ++j) a3[j] = fmaf(x, wr[j], a3[j]);
        }
    }
    // ---- layer 4: 32 -> 1 ----
    float o = b4[0];
#pragma unroll
    for (int k = 0; k < 32; ++k) o = fmaf(lrelu(a3[k]), w4[k], o);
    return o;
}

__global__ __launch_bounds__(64, 4)
void edge_mlp(const float* __restrict__ x_src, const float* __restrict__ x_dst,
              const int* __restrict__ eidx,
              const float* __restrict__ ew1, const float* __restrict__ eb1,
              const float* __restrict__ ew2, const float* __restrict__ eb2,
              const float* __restrict__ ew3, const float* __restrict__ eb3,
              const float* __restrict__ ew4, const float* __restrict__ eb4,
              const float* __restrict__ ww1, const float* __restrict__ wb1,
              const float* __restrict__ ww2, const float* __restrict__ wb2,
              const float* __restrict__ ww3, const float* __restrict__ wb3,
              const float* __restrict__ ww4, const float* __restrict__ wb4,
              float* __restrict__ out, int n_edges)
{
    __shared__ float hbuf[64 * 66];   // 16.9 KB: stride 66 words -> b64 reads 2-way (free)
    const int tid = threadIdx.x;
    const int e = blockIdx.x * 64 + tid;
    if (e >= n_edges) return;
    float* hrow = hbuf + tid * 66;

    const int s = eidx[e];
    const int d = eidx[n_edges + e];
    const float* rs = x_src + (size_t)s * H;
    const float* rd = x_dst + (size_t)d * H;

    float oe = mlp_eval(rs, rd, hrow, ew1, eb1, ew2, eb2, ew3, eb3, ew4, eb4);
    out[e] = oe;
    float ow = mlp_eval(rs, rd, hrow, ww1, wb1, ww2, wb2, ww3, wb3, ww4, wb4);
    out[n_edges + e] = ow;
}

extern "C" void kernel_launch(void* const* d_in, const int* in_sizes, int n_in,
                              void* d_out, int out_size, void* d_ws, size_t ws_size,
                              hipStream_t stream)
{
    const float* x_src = (const float*)d_in[0];
    const float* x_dst = (const float*)d_in[1];
    const int*   eidx  = (const int*)d_in[2];
    const float* ew1 = (const float*)d_in[3];
    const float* eb1 = (const float*)d_in[4];
    const float* ww1 = (const float*)d_in[5];
    const float* wb1 = (const float*)d_in[6];
    const float* ew2 = (const float*)d_in[7];
    const float* eb2 = (const float*)d_in[8];
    const float* ww2 = (const float*)d_in[9];
    const float* wb2 = (const float*)d_in[10];
    const float* ew3 = (const float*)d_in[11];
    const float* eb3 = (const float*)d_in[12];
    const float* ww3 = (const float*)d_in[13];
    const float* wb3 = (const float*)d_in[14];
    const float* ew4 = (const float*)d_in[15];
    const float* eb4 = (const float*)d_in[16];
    const float* ww4 = (const float*)d_in[17];
    const float* wb4 = (const float*)d_in[18];
    float* out = (float*)d_out;

    const int n_edges = in_sizes[2] / 2;   // 2 x E index array
    const int grid = (n_edges + 63) / 64;

    edge_mlp<<<grid, 64, 0, stream>>>(x_src, x_dst, eidx,
                                      ew1, eb1, ew2, eb2, ew3, eb3, ew4, eb4,
                                      ww1, wb1, ww2, wb2, ww3, wb3, ww4, wb4,
                                      out, n_edges);
}

// Round 2
// 705.603 us; speedup vs baseline: 3.3049x; 3.3049x over previous
//
#include <hip/hip_runtime.h>

// RegressorHybrid: per-edge 2x MLP (128->64->64->32->1, lrelu 0.01), E=2M, H=64.
// Round 2: MFMA f16 rewrite, transposed GEMM (M=hidden, N=16 edges, K=in).
//   - Hidden-dim permutation folded into packed weights so layer L's C/D frag is
//     layer L+1's B frag after in-lane lrelu+f16 repack (no LDS between layers).
//   - Weights/biases pre-packed to per-lane fragment order in d_ws by prep_frags;
//     w1/w2/w3 frags staged in 56KB LDS (2 blocks/CU), ds_read_b128 at lane*16.
//   - Node tables pre-converted to f16 in d_ws; gathered half8 loads ARE B1 frags.
// Layouts (verified refs): A[m=lane&15][k=(lane>>4)*8+j], B[k=(lane>>4)*8+j][n=lane&15],
//                          C/D[row=4*(lane>>4)+reg][col=lane&15].

typedef _Float16 half8  __attribute__((ext_vector_type(8)));
typedef _Float16 half4v __attribute__((ext_vector_type(4)));
typedef float    float4v __attribute__((ext_vector_type(4)));

#define LDS_PER_MLP 28672          // w1f 16384 + w2f 8192 + w3f 4096
#define LDS_TOTAL   57344
#define REST_PER_MLP 12288         // w4f 2048 + b1f 4096 + b2f 4096 + b3f 2048
#define W1F 0
#define W2F 16384
#define W3F 24576
#define RW4F 0
#define RB1F 2048
#define RB2F 6144
#define RB3F 10240
#define WS_REST_OFF 57344
#define WS_X16_OFF  81920          // 57344 + 2*12288

__device__ __forceinline__ float lrelu(float x) { return fmaxf(x, 0.01f * x); }

// inverse of the hidden permutation: B-position k holds hidden unit u(k)
__device__ __forceinline__ int uperm(int k) {
    return 16 * (2 * ((k >> 2) & 1) + ((k >> 5) & 1)) + 4 * ((k >> 3) & 3) + (k & 3);
}

// ---- pack one MLP's weights/biases into per-lane fragment order ----
__global__ void prep_frags(const float* __restrict__ w1, const float* __restrict__ b1,
                           const float* __restrict__ w2, const float* __restrict__ b2,
                           const float* __restrict__ w3, const float* __restrict__ b3,
                           const float* __restrict__ w4,
                           unsigned char* __restrict__ dstL,   // ws + m*LDS_PER_MLP
                           unsigned char* __restrict__ dstR)   // ws + WS_REST_OFF + m*REST_PER_MLP
{
    int idx = blockIdx.x * blockDim.x + threadIdx.x;
    if (idx < 8192) {                      // w1f: [16 frags][64 lanes][8 f16]
        int L = (idx >> 3) & 63, j = idx & 7, f = idx >> 9;
        int q = L >> 4, mm = L & 15, t = f >> 2, s = f & 3;
        int k = 32 * s + 8 * q + j;        // input feature (no perm on inputs)
        ((_Float16*)(dstL + W1F))[idx] = (_Float16)w1[k * 64 + 16 * t + mm];
        return;
    }
    idx -= 8192;
    if (idx < 4096) {                      // w2f: [8][64][8]
        int L = (idx >> 3) & 63, j = idx & 7, f = idx >> 9;
        int q = L >> 4, mm = L & 15, t = f >> 1, s = f & 1;
        int u = uperm(32 * s + 8 * q + j);
        ((_Float16*)(dstL + W2F))[idx] = (_Float16)w2[u * 64 + 16 * t + mm];
        return;
    }
    idx -= 4096;
    if (idx < 2048) {                      // w3f: [4][64][8]
        int L = (idx >> 3) & 63, j = idx & 7, f = idx >> 9;
        int q = L >> 4, mm = L & 15, t = f >> 1, s = f & 1;
        int u = uperm(32 * s + 8 * q + j);
        ((_Float16*)(dstL + W3F))[idx] = (_Float16)w3[u * 32 + 16 * t + mm];
        return;
    }
    idx -= 2048;
    if (idx < 512) {                       // w4f: [64 lanes][8 f32]
        int L = idx >> 3, j = idx & 7;
        int q = L >> 4, t = j >> 2, r = j & 3;
        ((float*)(dstR + RW4F))[idx] = w4[16 * t + 4 * q + r];
        return;
    }
    idx -= 512;
    if (idx < 1024) {                      // b1f: [4 ntile][64 lanes][4 f32]
        int t = idx >> 8, L = (idx >> 2) & 63, r = idx & 3, q = L >> 4;
        ((float*)(dstR + RB1F))[idx] = b1[16 * t + 4 * q + r];
        return;
    }
    idx -= 1024;
    if (idx < 1024) {                      // b2f
        int t = idx >> 8, L = (idx >> 2) & 63, r = idx & 3, q = L >> 4;
        ((float*)(dstR + RB2F))[idx] = b2[16 * t + 4 * q + r];
        return;
    }
    idx -= 1024;
    if (idx < 512) {                       // b3f: [2][64][4]
        int t = idx >> 8, L = (idx >> 2) & 63, r = idx & 3, q = L >> 4;
        ((float*)(dstR + RB3F))[idx] = b3[16 * t + 4 * q + r];
        return;
    }
}

// ---- convert node tables fp32 -> f16 ----
__global__ void prep_nodes(const float* __restrict__ xs, const float* __restrict__ xd,
                           _Float16* __restrict__ os, _Float16* __restrict__ od, int n4)
{
    int stride = gridDim.x * blockDim.x;
    for (int i = blockIdx.x * blockDim.x + threadIdx.x; i < n4; i += stride) {
        float4v a = ((const float4v*)xs)[i];
        float4v b = ((const float4v*)xd)[i];
        half4v ha, hb;
#pragma unroll
        for (int j = 0; j < 4; ++j) { ha[j] = (_Float16)a[j]; hb[j] = (_Float16)b[j]; }
        ((half4v*)os)[i] = ha;
        ((half4v*)od)[i] = hb;
    }
}

// repack C/D frags (t=s and t=s+2) into next layer's B frag (lrelu + f16)
__device__ __forceinline__ half8 repack2(float4v lo, float4v hi) {
    half8 r;
#pragma unroll
    for (int j = 0; j < 4; ++j) r[j] = (_Float16)lrelu(lo[j]);
#pragma unroll
    for (int j = 0; j < 4; ++j) r[4 + j] = (_Float16)lrelu(hi[j]);
    return r;
}

__global__ __launch_bounds__(256, 2)
void edge_mlp_mfma(const unsigned char* __restrict__ ws,
                   const _Float16* __restrict__ xs, const _Float16* __restrict__ xd,
                   const int* __restrict__ eidx,
                   const float* __restrict__ eb4p, const float* __restrict__ wb4p,
                   float* __restrict__ out, int nE, int ntiles)
{
    __shared__ unsigned char lds[LDS_TOTAL];
    {   // stage packed w1/w2/w3 frags for both MLPs (coalesced uint4 copy)
        const uint4* s = (const uint4*)ws;
        uint4* d = (uint4*)lds;
        for (int i = threadIdx.x; i < LDS_TOTAL / 16; i += 256) d[i] = s[i];
    }
    __syncthreads();

    const int lane = threadIdx.x & 63;
    const int q = lane >> 4, n = lane & 15;
    const int wid = (blockIdx.x << 2) | (threadIdx.x >> 6);
    const int nwaves = gridDim.x << 2;

    // hoist bias / w4 fragments (read once per wave, from global)
    float4v b1v[2][4], b2v[2][4], b3v[2][2], w4v[2][2];
    float b4s[2];
    const float* b4p[2] = { eb4p, wb4p };
#pragma unroll
    for (int m = 0; m < 2; ++m) {
        const unsigned char* rb = ws + WS_REST_OFF + m * REST_PER_MLP;
#pragma unroll
        for (int t = 0; t < 4; ++t) b1v[m][t] = *(const float4v*)(rb + RB1F + (t * 64 + lane) * 16);
#pragma unroll
        for (int t = 0; t < 4; ++t) b2v[m][t] = *(const float4v*)(rb + RB2F + (t * 64 + lane) * 16);
#pragma unroll
        for (int t = 0; t < 2; ++t) b3v[m][t] = *(const float4v*)(rb + RB3F + (t * 64 + lane) * 16);
        w4v[m][0] = *(const float4v*)(rb + RW4F + lane * 32);
        w4v[m][1] = *(const float4v*)(rb + RW4F + lane * 32 + 16);
        b4s[m] = b4p[m][0];
    }

#pragma unroll 1
    for (int tile = wid; tile < ntiles; tile += nwaves) {
        int e = tile * 16 + n;
        int ec = e < nE ? e : nE - 1;
        int si = eidx[ec];
        int di = eidx[nE + ec];
        const _Float16* rs = xs + (size_t)si * 64;
        const _Float16* rd = xd + (size_t)di * 64;
        half8 B1[4];                        // gathered loads ARE the B1 fragments
        B1[0] = *(const half8*)(rs + 8 * q);
        B1[1] = *(const half8*)(rs + 32 + 8 * q);
        B1[2] = *(const half8*)(rd + 8 * q);
        B1[3] = *(const half8*)(rd + 32 + 8 * q);

        float res[2];
#pragma unroll
        for (int m = 0; m < 2; ++m) {
            const unsigned char* mb = lds + m * LDS_PER_MLP;
            // ---- layer 1: 128 -> 64 (4 ntiles x 4 ksteps), bias via C-init ----
            float4v acc[4];
#pragma unroll
            for (int t = 0; t < 4; ++t) {
                acc[t] = b1v[m][t];
#pragma unroll
                for (int s = 0; s < 4; ++s) {
                    half8 A = *(const half8*)(mb + W1F + ((t * 4 + s) * 64 + lane) * 16);
                    acc[t] = __builtin_amdgcn_mfma_f32_16x16x32_f16(A, B1[s], acc[t], 0, 0, 0);
                }
            }
            // ---- layer 2: 64 -> 64 ----
            half8 B2[2] = { repack2(acc[0], acc[2]), repack2(acc[1], acc[3]) };
            float4v acc2[4];
#pragma unroll
            for (int t = 0; t < 4; ++t) {
                acc2[t] = b2v[m][t];
#pragma unroll
                for (int s = 0; s < 2; ++s) {
                    half8 A = *(const half8*)(mb + W2F + ((t * 2 + s) * 64 + lane) * 16);
                    acc2[t] = __builtin_amdgcn_mfma_f32_16x16x32_f16(A, B2[s], acc2[t], 0, 0, 0);
                }
            }
            // ---- layer 3: 64 -> 32 ----
            half8 B3[2] = { repack2(acc2[0], acc2[2]), repack2(acc2[1], acc2[3]) };
            float4v acc3[2];
#pragma unroll
            for (int t = 0; t < 2; ++t) {
                acc3[t] = b3v[m][t];
#pragma unroll
                for (int s = 0; s < 2; ++s) {
                    half8 A = *(const half8*)(mb + W3F + ((t * 2 + s) * 64 + lane) * 16);
                    acc3[t] = __builtin_amdgcn_mfma_f32_16x16x32_f16(A, B3[s], acc3[t], 0, 0, 0);
                }
            }
            // ---- layer 4: 32 -> 1 (per-lane dot + cross-quad reduce) ----
            float o = 0.f;
#pragma unroll
            for (int r = 0; r < 4; ++r) o = fmaf(lrelu(acc3[0][r]), w4v[m][0][r], o);
#pragma unroll
            for (int r = 0; r < 4; ++r) o = fmaf(lrelu(acc3[1][r]), w4v[m][1][r], o);
            o += __shfl_xor(o, 16, 64);
            o += __shfl_xor(o, 32, 64);
            res[m] = o + b4s[m];
        }
        if (q == 0 && e < nE) {
            out[e] = res[0];
            out[nE + e] = res[1];
        }
    }
}

extern "C" void kernel_launch(void* const* d_in, const int* in_sizes, int n_in,
                              void* d_out, int out_size, void* d_ws, size_t ws_size,
                              hipStream_t stream)
{
    const float* x_src = (const float*)d_in[0];
    const float* x_dst = (const float*)d_in[1];
    const int*   eidx  = (const int*)d_in[2];
    const float* ew1 = (const float*)d_in[3];
    const float* eb1 = (const float*)d_in[4];
    const float* ww1 = (const float*)d_in[5];
    const float* wb1 = (const float*)d_in[6];
    const float* ew2 = (const float*)d_in[7];
    const float* eb2 = (const float*)d_in[8];
    const float* ww2 = (const float*)d_in[9];
    const float* wb2 = (const float*)d_in[10];
    const float* ew3 = (const float*)d_in[11];
    const float* eb3 = (const float*)d_in[12];
    const float* ww3 = (const float*)d_in[13];
    const float* wb3 = (const float*)d_in[14];
    const float* ew4 = (const float*)d_in[15];
    const float* eb4 = (const float*)d_in[16];
    const float* ww4 = (const float*)d_in[17];
    const float* wb4 = (const float*)d_in[18];
    float* out = (float*)d_out;

    const int nE = in_sizes[2] / 2;          // 2 x E index array (int32)
    const int nNodeElems = in_sizes[0];      // N_NODES * 64
    unsigned char* ws = (unsigned char*)d_ws;
    _Float16* xs16 = (_Float16*)(ws + WS_X16_OFF);
    _Float16* xd16 = xs16 + nNodeElems;

    prep_frags<<<68, 256, 0, stream>>>(ew1, eb1, ew2, eb2, ew3, eb3, ew4,
                                       ws, ws + WS_REST_OFF);
    prep_frags<<<68, 256, 0, stream>>>(ww1, wb1, ww2, wb2, ww3, wb3, ww4,
                                       ws + LDS_PER_MLP, ws + WS_REST_OFF + REST_PER_MLP);
    prep_nodes<<<1024, 256, 0, stream>>>(x_src, x_dst, xs16, xd16, nNodeElems / 4);

    const int ntiles = (nE + 15) / 16;
    edge_mlp_mfma<<<512, 256, 0, stream>>>(ws, xs16, xd16, eidx, eb4, wb4,
                                           out, nE, ntiles);
}